// Round 1
// baseline (6125.178 us; speedup 1.0000x reference)
//
#include <hip/hip_runtime.h>
#include <hip/hip_bf16.h>
#include <stdint.h>

// ============================================================================
// bayesian_nn: 150 MC samples of a 3x512 hidden MLP with KFAC-sampled weights.
// Round 1: correctness-first. Exact JAX threefry2x32 PRNG + XLA erfinv,
// fp32 tiled GEMMs. JAX_PARTITIONABLE selects the PRNG counter scheme:
//   1 = jax_threefry_partitionable=True  (default in JAX >= 0.4.36)
//   0 = legacy/original mode
// If this round fails with absmax ~300-500 -> flip to 0.
// ============================================================================

#define JAX_PARTITIONABLE 1

#define NSAMP 150

typedef unsigned int u32;

// ---------------------------------------------------------------- threefry --
__device__ __forceinline__ u32 rotl32(u32 x, int r){ return (x<<r)|(x>>(32-r)); }

__device__ __forceinline__ void tf_block(u32 k0, u32 k1, u32 x0, u32 x1, u32& o0, u32& o1){
  u32 k2 = k0 ^ k1 ^ 0x1BD11BDAu;
  x0 += k0; x1 += k1;
#define TF_R4(a,b,c,d) \
  x0+=x1; x1=rotl32(x1,a); x1^=x0; \
  x0+=x1; x1=rotl32(x1,b); x1^=x0; \
  x0+=x1; x1=rotl32(x1,c); x1^=x0; \
  x0+=x1; x1=rotl32(x1,d); x1^=x0;
  TF_R4(13,15,26,6)  x0+=k1; x1+=k2+1u;
  TF_R4(17,29,16,24) x0+=k2; x1+=k0+2u;
  TF_R4(13,15,26,6)  x0+=k0; x1+=k1+3u;
  TF_R4(17,29,16,24) x0+=k1; x1+=k2+4u;
  TF_R4(13,15,26,6)  x0+=k2; x1+=k0+5u;
#undef TF_R4
  o0=x0; o1=x1;
}

// random_bits(key, 32, n)[e]  (n even in all uses here)
__device__ __forceinline__ u32 jax_bits(u32 kh, u32 kl, u32 e, u32 n){
#if JAX_PARTITIONABLE
  // 64-bit counter e (hi=0, lo=e); bits = out0 ^ out1
  u32 o0,o1; tf_block(kh,kl,0u,e,o0,o1); return o0^o1;
#else
  // original: counts=iota(n); x0=counts[0:n/2], x1=counts[n/2:n]; out=concat(r0,r1)
  u32 h = n>>1; u32 o0,o1;
  if (e < h) { tf_block(kh,kl,e,h+e,o0,o1); return o0; }
  tf_block(kh,kl,e-h,e,o0,o1); return o1;
#endif
}

// ------------------------------------------------- XLA erfinv + normal map --
__device__ __forceinline__ float erfinv_xla(float x){
  float w = -log1pf(-x*x);
  float p;
  if (w < 5.0f) {
    w -= 2.5f;
    p =              2.81022636e-08f;
    p = fmaf(p, w,   3.43273939e-07f);
    p = fmaf(p, w,  -3.5233877e-06f);
    p = fmaf(p, w,  -4.39150654e-06f);
    p = fmaf(p, w,   0.00021858087f);
    p = fmaf(p, w,  -0.00125372503f);
    p = fmaf(p, w,  -0.00417768164f);
    p = fmaf(p, w,   0.246640727f);
    p = fmaf(p, w,   1.50140941f);
  } else {
    w = sqrtf(w) - 3.0f;
    p =             -0.000200214257f;
    p = fmaf(p, w,   0.000100950558f);
    p = fmaf(p, w,   0.00134934322f);
    p = fmaf(p, w,  -0.00367342844f);
    p = fmaf(p, w,   0.00573950773f);
    p = fmaf(p, w,  -0.0076224613f);
    p = fmaf(p, w,   0.00943887047f);
    p = fmaf(p, w,   1.00167406f);
    p = fmaf(p, w,   2.83297682f);
  }
  return p * x;
}

__device__ __forceinline__ float bits_to_normal(u32 bits){
  // uniform in [lo, 1), lo = nextafter(-1,0); (hi-lo) rounds to exactly 2.0f
  float f = __uint_as_float((bits >> 9) | 0x3F800000u) - 1.0f;   // [0,1)
  const float lo = -0.99999994f;                                  // 0xBF7FFFFF
  float u = fmaf(f, 2.0f, lo);
  u = fmaxf(u, lo);
  return 1.41421356237f * erfinv_xla(u);                          // sqrt(2)*erfinv
}

// ------------------------------------------------------------- key kernel --
// keys[s*8 + {0..7}] = k0h,k0l,k1h,k1l,k2h,k2l,k3h,k3l for sample s
__global__ void k_keys(u32* __restrict__ keys){
  int s = threadIdx.x;
  if (s >= NSAMP) return;
  u32 sh, sl;
#if JAX_PARTITIONABLE
  // foldlike split(key(42)=(0,42), 150): key_s = block((0,42),(0,s))
  tf_block(0u,42u,0u,(u32)s,sh,sl);
#else
  // original split: counts=iota(300); flat[i] = (i<150 ? r0(block i) : r1(block i-150))
  {
    u32 i0 = 2u*s, i1 = 2u*s+1u, o0,o1;
    u32 j0 = (i0 < 150u) ? i0 : i0-150u;
    tf_block(0u,42u,j0,150u+j0,o0,o1);
    sh = (i0 < 150u) ? o0 : o1;
    u32 j1 = (i1 < 150u) ? i1 : i1-150u;
    tf_block(0u,42u,j1,150u+j1,o0,o1);
    sl = (i1 < 150u) ? o0 : o1;
  }
#endif
  u32* k = keys + s*8;
#if JAX_PARTITIONABLE
  tf_block(sh,sl,0u,0u,k[0],k[1]);
  tf_block(sh,sl,0u,1u,k[2],k[3]);
  tf_block(sh,sl,0u,2u,k[4],k[5]);
  tf_block(sh,sl,0u,3u,k[6],k[7]);
#else
  u32 f[8];
  for (u32 j=0;j<4;++j){ u32 o0,o1; tf_block(sh,sl,j,4u+j,o0,o1); f[j]=o0; f[4u+j]=o1; }
  for (int i=0;i<8;++i) k[i]=f[i];
#endif
}

// ------------------------------------------------------ rWh generation ------
// rW[sl][e] = normal * sqrt(exp(2*v_Wh[e])), e in [0,786432), 768 blocks/sample
__global__ __launch_bounds__(256) void k_genrw(const float* __restrict__ v_Wh,
                                               const u32* __restrict__ keys,
                                               float* __restrict__ rW, int s0){
  int sl = blockIdx.x / 768;
  int bi = blockIdx.x - sl*768;
  int e4 = (bi*256 + threadIdx.x) * 4;
  const u32* k = keys + (size_t)(s0+sl)*8;
  u32 kh = k[0], kl = k[1];
  float4 v = *(const float4*)(v_Wh + e4);
  float4 r;
  r.x = bits_to_normal(jax_bits(kh,kl,(u32)(e4+0),786432u)) * sqrtf(expf(2.f*v.x));
  r.y = bits_to_normal(jax_bits(kh,kl,(u32)(e4+1),786432u)) * sqrtf(expf(2.f*v.y));
  r.z = bits_to_normal(jax_bits(kh,kl,(u32)(e4+2),786432u)) * sqrtf(expf(2.f*v.z));
  r.w = bits_to_normal(jax_bits(kh,kl,(u32)(e4+3),786432u)) * sqrtf(expf(2.f*v.w));
  *(float4*)(rW + (size_t)sl*786432 + e4) = r;
}

// --------------------------------------------- small weights (bh, Wo, bo) ---
__global__ __launch_bounds__(512) void k_small(const float* __restrict__ mu_bh,
                                               const float* __restrict__ v_bh,
                                               const float* __restrict__ vb_bh,
                                               const float* __restrict__ mu_Wo,
                                               const float* __restrict__ v_Wo,
                                               const float* __restrict__ vo_Wo,
                                               const float* __restrict__ vi_Wo,
                                               const float* __restrict__ mu_bo,
                                               const float* __restrict__ v_bo,
                                               const float* __restrict__ vb_bo,
                                               const u32* __restrict__ keys,
                                               float* __restrict__ bh_all,
                                               float* __restrict__ Wo_all,
                                               float* __restrict__ bo_all){
  int s = blockIdx.x, t = threadIdx.x;
  const u32* k = keys + (size_t)s*8;
  __shared__ __align__(16) float rbh[1536];
  __shared__ __align__(16) float t2[1024];
  // rbh[l,a] = normal * sqrt(exp(2 v_bh))
  for (int e=t; e<1536; e+=512)
    rbh[e] = bits_to_normal(jax_bits(k[2],k[3],(u32)e,1536u)) * sqrtf(expf(2.f*v_bh[e]));
  // rWo (2x512) then t2 = vo_Wo @ rWo  (2x512)
  {
    float r0 = bits_to_normal(jax_bits(k[4],k[5],(u32)t,      1024u)) * sqrtf(expf(2.f*v_Wo[t]));
    float r1 = bits_to_normal(jax_bits(k[4],k[5],(u32)(t+512),1024u)) * sqrtf(expf(2.f*v_Wo[t+512]));
    t2[t]     = vo_Wo[0]*r0 + vo_Wo[1]*r1;
    t2[t+512] = vo_Wo[2]*r0 + vo_Wo[3]*r1;
  }
  __syncthreads();
  // bh[s,l,o] = vb_bh[l,o,:] . rbh[l,:] + mu_bh[l,o]
  for (int e=t; e<1536; e+=512){
    int l = e >> 9;
    const float* row = vb_bh + (size_t)e*512;
    const float* rb = rbh + (l<<9);
    float acc = 0.f;
    for (int a=0;a<512;a+=4){
      float4 vv = *(const float4*)(row+a);
      acc += vv.x*rb[a] + vv.y*rb[a+1] + vv.z*rb[a+2] + vv.w*rb[a+3];
    }
    bh_all[(size_t)s*1536+e] = acc + mu_bh[e];
  }
  // Wo[s,c,i] = t2[c,:] . vi_Wo[i,:] + mu_Wo[c,i]
  {
    const float* row = vi_Wo + (size_t)t*512;
    float a0=0.f, a1=0.f;
    for (int b=0;b<512;b+=4){
      float4 vv = *(const float4*)(row+b);
      a0 += vv.x*t2[b]    +vv.y*t2[b+1]    +vv.z*t2[b+2]    +vv.w*t2[b+3];
      a1 += vv.x*t2[512+b]+vv.y*t2[512+b+1]+vv.z*t2[512+b+2]+vv.w*t2[512+b+3];
    }
    Wo_all[(size_t)s*1024 + t]       = a0 + mu_Wo[t];
    Wo_all[(size_t)s*1024 + 512 + t] = a1 + mu_Wo[512+t];
  }
  // bo[s,c] = vb_bo[c,:] . rbo + mu_bo[c]
  if (t < 2){
    float rb0 = bits_to_normal(jax_bits(k[6],k[7],0u,2u)) * sqrtf(expf(2.f*v_bo[0]));
    float rb1 = bits_to_normal(jax_bits(k[6],k[7],1u,2u)) * sqrtf(expf(2.f*v_bo[1]));
    bo_all[(size_t)s*2+t] = vb_bo[t*2+0]*rb0 + vb_bo[t*2+1]*rb1 + mu_bo[t];
  }
}

// --------------------------------------------------- fp32 tiled 512^3 GEMM --
// C[m,n] = sum_k A[m,k] * (TRANSB ? B[n,k] : B[k,n])  (+ epilogue)
// EPI: 0 none; 1: += E[m,n]; 2: += E[n], relu
template<bool TRANSB, int EPI>
__device__ __forceinline__ void gemm512(const float* __restrict__ A,
                                        const float* __restrict__ B,
                                        const float* __restrict__ E,
                                        float* __restrict__ C){
  __shared__ __align__(16) float As[32][68];
  __shared__ __align__(16) float Bs[32][68];
  const int t = threadIdx.x;
  const int m0 = blockIdx.y*64, n0 = blockIdx.x*64;
  const int ty = t>>4, tx = t&15;
  float acc[4][4] = {};
  for (int k0 = 0; k0 < 512; k0 += 32) {
    #pragma unroll
    for (int it = 0; it < 2; ++it) {                 // A tile -> As[k][m]
      int idx = t + it*256;
      int r = idx >> 3, c = (idx & 7) << 2;
      float4 v = *(const float4*)(A + (size_t)(m0 + r)*512 + k0 + c);
      As[c+0][r] = v.x; As[c+1][r] = v.y; As[c+2][r] = v.z; As[c+3][r] = v.w;
    }
    if (TRANSB) {                                    // B[n][k] -> Bs[k][n]
      #pragma unroll
      for (int it = 0; it < 2; ++it) {
        int idx = t + it*256;
        int r = idx >> 3, c = (idx & 7) << 2;
        float4 v = *(const float4*)(B + (size_t)(n0 + r)*512 + k0 + c);
        Bs[c+0][r] = v.x; Bs[c+1][r] = v.y; Bs[c+2][r] = v.z; Bs[c+3][r] = v.w;
      }
    } else {                                         // B[k][n] -> Bs[k][n]
      #pragma unroll
      for (int it = 0; it < 2; ++it) {
        int idx = t + it*256;
        int r = idx >> 4, c = (idx & 15) << 2;
        *(float4*)&Bs[r][c] = *(const float4*)(B + (size_t)(k0 + r)*512 + n0 + c);
      }
    }
    __syncthreads();
    #pragma unroll
    for (int kk = 0; kk < 32; ++kk) {
      float4 a = *(const float4*)&As[kk][ty*4];
      float4 b = *(const float4*)&Bs[kk][tx*4];
      float av[4] = {a.x,a.y,a.z,a.w}, bv[4] = {b.x,b.y,b.z,b.w};
      #pragma unroll
      for (int i=0;i<4;++i)
        #pragma unroll
        for (int j=0;j<4;++j)
          acc[i][j] = fmaf(av[i], bv[j], acc[i][j]);
    }
    __syncthreads();
  }
  float4 bias;
  if (EPI==2) bias = *(const float4*)(E + n0 + tx*4);
  #pragma unroll
  for (int i=0;i<4;++i){
    int m = m0 + ty*4 + i;
    float4 v = make_float4(acc[i][0],acc[i][1],acc[i][2],acc[i][3]);
    if (EPI==1){
      float4 e = *(const float4*)(E + (size_t)m*512 + n0 + tx*4);
      v.x+=e.x; v.y+=e.y; v.z+=e.z; v.w+=e.w;
    }
    if (EPI==2){
      v.x = fmaxf(v.x+bias.x, 0.f); v.y = fmaxf(v.y+bias.y, 0.f);
      v.z = fmaxf(v.z+bias.z, 0.f); v.w = fmaxf(v.w+bias.w, 0.f);
    }
    *(float4*)(C + (size_t)m*512 + n0 + tx*4) = v;
  }
}

// tmp[s,l] = vo_Wh[l] @ rW[s,l]        (NN)
__global__ __launch_bounds__(256) void k_tmp(const float* __restrict__ vo_Wh,
                                             const float* __restrict__ rW,
                                             float* __restrict__ tmp){
  int q = blockIdx.z;
  gemm512<false,0>(vo_Wh + (size_t)(q%3)*262144, rW + (size_t)q*262144,
                   nullptr, tmp + (size_t)q*262144);
}

// Wh[s,l] = tmp[s,l] @ vi_Wh[l]^T + mu_Wh[l]    (NT, matrix epilogue)
__global__ __launch_bounds__(256) void k_wh(const float* __restrict__ tmp,
                                            const float* __restrict__ vi_Wh,
                                            const float* __restrict__ mu_Wh,
                                            float* __restrict__ Wh){
  int q = blockIdx.z; int l = q%3;
  gemm512<true,1>(tmp + (size_t)q*262144, vi_Wh + (size_t)l*262144,
                  mu_Wh + (size_t)l*262144, Wh + (size_t)q*262144);
}

// h_out = relu(h_in @ Wh[s,l]^T + bh[s,l])      (NT, bias+relu)
// hbuf[s]: [0..262143] = h0, [262144..524287] = h1 ; l0: x->h0, l1: h0->h1, l2: h1->h0
__global__ __launch_bounds__(256) void k_fwd(const float* __restrict__ x,
                                             const float* __restrict__ Wh,
                                             const float* __restrict__ bh_all,
                                             float* __restrict__ hbuf, int l, int s0){
  int sl = blockIdx.z;
  float* hb = hbuf + (size_t)sl*786432;
  const float* A = (l==0) ? x : (l==1 ? hb : hb + 262144);
  float* O = (l==1) ? hb + 262144 : hb;
  gemm512<true,2>(A, Wh + (size_t)sl*786432 + (size_t)l*262144,
                  bh_all + (size_t)(s0+sl)*1536 + (size_t)l*512, O);
}

// out[s,b,c] = h[b,:] . Wo[s,c,:] + bo[s,c]
__global__ __launch_bounds__(256) void k_out(const float* __restrict__ hbuf,
                                             const float* __restrict__ Wo_all,
                                             const float* __restrict__ bo_all,
                                             float* __restrict__ out, int s0){
  int sl = blockIdx.x;
  int b = blockIdx.y*256 + threadIdx.x;
  const float* h  = hbuf + (size_t)sl*786432 + (size_t)b*512;
  int s = s0 + sl;
  const float* W0 = Wo_all + (size_t)s*1024;
  const float* W1 = W0 + 512;
  float a0=0.f, a1=0.f;
  for (int i=0;i<512;i+=4){
    float4 hv = *(const float4*)(h+i);
    float4 w0 = *(const float4*)(W0+i);
    float4 w1 = *(const float4*)(W1+i);
    a0 += hv.x*w0.x + hv.y*w0.y + hv.z*w0.z + hv.w*w0.w;
    a1 += hv.x*w1.x + hv.y*w1.y + hv.z*w1.z + hv.w*w1.w;
  }
  out[((size_t)s*512 + b)*2 + 0] = a0 + bo_all[(size_t)s*2+0];
  out[((size_t)s*512 + b)*2 + 1] = a1 + bo_all[(size_t)s*2+1];
}

// ---------------------------------------------------------------- launch ----
extern "C" void kernel_launch(void* const* d_in, const int* in_sizes, int n_in,
                              void* d_out, int out_size, void* d_ws, size_t ws_size,
                              hipStream_t stream){
  const float* x      = (const float*)d_in[0];
  const float* mu_Wh  = (const float*)d_in[1];
  const float* v_Wh   = (const float*)d_in[2];
  const float* vo_Wh  = (const float*)d_in[3];
  const float* vi_Wh  = (const float*)d_in[4];
  const float* mu_bh  = (const float*)d_in[5];
  const float* v_bh   = (const float*)d_in[6];
  const float* vb_bh  = (const float*)d_in[7];
  const float* mu_Wo  = (const float*)d_in[8];
  const float* v_Wo   = (const float*)d_in[9];
  const float* vo_Wo  = (const float*)d_in[10];
  const float* vi_Wo  = (const float*)d_in[11];
  const float* mu_bo  = (const float*)d_in[12];
  const float* v_bo   = (const float*)d_in[13];
  const float* vb_bo  = (const float*)d_in[14];
  float* out = (float*)d_out;

  char* ws = (char*)d_ws;
  // layout: keys(4800B) | bh_all(150*1536f) | Wo_all(150*1024f) | bo_all(150*2f) | big
  u32*   keys   = (u32*)ws;
  float* bh_all = (float*)(ws + 4864);
  float* Wo_all = (float*)(ws + 4864 + 921600);
  float* bo_all = (float*)(ws + 4864 + 921600 + 614400);
  const size_t big_off = 1542144;            // 256B-aligned
  const size_t per_sample_f = 2u*786432u;    // bufA + bufB floats per sample
  size_t avail_f = (ws_size > big_off) ? (ws_size - big_off)/4 : 0;
  int C = (int)(avail_f / per_sample_f);
  if (C < 1) C = 1;
  if (C > NSAMP) C = NSAMP;
  float* bufA = (float*)(ws + big_off);            // rWh -> Wh   [C][3][512][512]
  float* bufB = bufA + (size_t)C*786432;           // tmp -> h ping-pong

  hipLaunchKernelGGL(k_keys, dim3(1), dim3(256), 0, stream, keys);
  hipLaunchKernelGGL(k_small, dim3(NSAMP), dim3(512), 0, stream,
                     mu_bh, v_bh, vb_bh, mu_Wo, v_Wo, vo_Wo, vi_Wo,
                     mu_bo, v_bo, vb_bo, keys, bh_all, Wo_all, bo_all);

  for (int s0 = 0; s0 < NSAMP; s0 += C){
    int Cc = (NSAMP - s0 < C) ? (NSAMP - s0) : C;
    hipLaunchKernelGGL(k_genrw, dim3(Cc*768), dim3(256), 0, stream, v_Wh, keys, bufA, s0);
    hipLaunchKernelGGL(k_tmp,   dim3(8,8,Cc*3), dim3(256), 0, stream, vo_Wh, bufA, bufB);
    hipLaunchKernelGGL(k_wh,    dim3(8,8,Cc*3), dim3(256), 0, stream, bufB, vi_Wh, mu_Wh, bufA);
    for (int l = 0; l < 3; ++l)
      hipLaunchKernelGGL(k_fwd, dim3(8,8,Cc), dim3(256), 0, stream, x, bufA, bh_all, bufB, l, s0);
    hipLaunchKernelGGL(k_out,   dim3(Cc,2), dim3(256), 0, stream, bufB, Wo_all, bo_all, out, s0);
  }
  (void)in_sizes; (void)n_in; (void)out_size;
}

// Round 3
// 1479.400 us; speedup vs baseline: 4.1403x; 4.1403x over previous
//
#include <hip/hip_runtime.h>
#include <hip/hip_bf16.h>
#include <stdint.h>

// ============================================================================
// bayesian_nn round 2 (resubmit — R2 bench hit GPUAcquisitionTimeout):
// bf16 MFMA GEMMs (m97 structure: 128^2 tile, BK=32, global_load_lds x16),
// single-chunk pipeline (ws ~1GB), rW generated pre-transposed so every GEMM
// is NT with row-major-K operands.
// PRNG: JAX partitionable threefry (verified bit-correct in round 1).
// ============================================================================

#define NSAMP 150

typedef unsigned int u32;
typedef unsigned short ushort_t;
using short8 = __attribute__((ext_vector_type(8))) short;
using us8    = __attribute__((ext_vector_type(8))) unsigned short;
using us4    = __attribute__((ext_vector_type(4))) unsigned short;
using f32x4  = __attribute__((ext_vector_type(4))) float;

// ---------------------------------------------------------------- threefry --
__device__ __forceinline__ u32 rotl32(u32 x, int r){ return (x<<r)|(x>>(32-r)); }

__device__ __forceinline__ void tf_block(u32 k0, u32 k1, u32 x0, u32 x1, u32& o0, u32& o1){
  u32 k2 = k0 ^ k1 ^ 0x1BD11BDAu;
  x0 += k0; x1 += k1;
#define TF_R4(a,b,c,d) \
  x0+=x1; x1=rotl32(x1,a); x1^=x0; \
  x0+=x1; x1=rotl32(x1,b); x1^=x0; \
  x0+=x1; x1=rotl32(x1,c); x1^=x0; \
  x0+=x1; x1=rotl32(x1,d); x1^=x0;
  TF_R4(13,15,26,6)  x0+=k1; x1+=k2+1u;
  TF_R4(17,29,16,24) x0+=k2; x1+=k0+2u;
  TF_R4(13,15,26,6)  x0+=k0; x1+=k1+3u;
  TF_R4(17,29,16,24) x0+=k1; x1+=k2+4u;
  TF_R4(13,15,26,6)  x0+=k2; x1+=k0+5u;
#undef TF_R4
  o0=x0; o1=x1;
}

// partitionable random_bits(key,32,n)[e]: 64-bit counter (0,e), out0^out1
__device__ __forceinline__ u32 jax_bits(u32 kh, u32 kl, u32 e){
  u32 o0,o1; tf_block(kh,kl,0u,e,o0,o1); return o0^o1;
}

// ------------------------------------------------- XLA erfinv + normal map --
__device__ __forceinline__ float erfinv_xla(float x){
  float w = -log1pf(-x*x);
  float p;
  if (w < 5.0f) {
    w -= 2.5f;
    p =              2.81022636e-08f;
    p = fmaf(p, w,   3.43273939e-07f);
    p = fmaf(p, w,  -3.5233877e-06f);
    p = fmaf(p, w,  -4.39150654e-06f);
    p = fmaf(p, w,   0.00021858087f);
    p = fmaf(p, w,  -0.00125372503f);
    p = fmaf(p, w,  -0.00417768164f);
    p = fmaf(p, w,   0.246640727f);
    p = fmaf(p, w,   1.50140941f);
  } else {
    w = sqrtf(w) - 3.0f;
    p =             -0.000200214257f;
    p = fmaf(p, w,   0.000100950558f);
    p = fmaf(p, w,   0.00134934322f);
    p = fmaf(p, w,  -0.00367342844f);
    p = fmaf(p, w,   0.00573950773f);
    p = fmaf(p, w,  -0.0076224613f);
    p = fmaf(p, w,   0.00943887047f);
    p = fmaf(p, w,   1.00167406f);
    p = fmaf(p, w,   2.83297682f);
  }
  return p * x;
}

__device__ __forceinline__ float bits_to_normal(u32 bits){
  float f = __uint_as_float((bits >> 9) | 0x3F800000u) - 1.0f;   // [0,1)
  const float lo = -0.99999994f;
  float u = fmaf(f, 2.0f, lo);
  u = fmaxf(u, lo);
  return 1.41421356237f * erfinv_xla(u);
}

// ------------------------------------------------------------- bf16 utils --
__device__ __forceinline__ ushort_t f2bf(float x){
  u32 u = __float_as_uint(x);
  u32 r = (u + 0x7FFFu + ((u>>16)&1u)) >> 16;
  return (ushort_t)r;
}
__device__ __forceinline__ float bf2f(ushort_t u){ return __uint_as_float(((u32)u)<<16); }

__device__ __forceinline__ void gload16(const void* g, void* l){
  __builtin_amdgcn_global_load_lds((const __attribute__((address_space(1))) void*)g,
                                   (__attribute__((address_space(3))) void*)l, 16, 0, 0);
}

// ------------------------------------------------------------- key kernel --
__global__ void k_keys(u32* __restrict__ keys){
  int s = threadIdx.x;
  if (s >= NSAMP) return;
  u32 sh, sl;
  tf_block(0u,42u,0u,(u32)s,sh,sl);        // foldlike split(key(42),150)
  u32* k = keys + s*8;
  tf_block(sh,sl,0u,0u,k[0],k[1]);
  tf_block(sh,sl,0u,1u,k[2],k[3]);
  tf_block(sh,sl,0u,2u,k[4],k[5]);
  tf_block(sh,sl,0u,3u,k[6],k[7]);
}

// ----------------------------------------------- sigmaT (transpose) + cvt --
// sigT[l][b][a] = sqrt(exp(2*v_Wh[l][a][b]))
__global__ void k_sigt(const float* __restrict__ v, float* __restrict__ sT){
  __shared__ float tile[32][33];
  int lw = blockIdx.z;
  int a0 = blockIdx.y*32, b0 = blockIdx.x*32;
  const float* src = v + (size_t)lw*262144;
  #pragma unroll
  for (int i=0;i<4;++i){
    int a = a0 + threadIdx.y + i*8;
    tile[threadIdx.y + i*8][threadIdx.x] = src[(size_t)a*512 + b0 + threadIdx.x];
  }
  __syncthreads();
  float* dst = sT + (size_t)lw*262144;
  #pragma unroll
  for (int i=0;i<4;++i){
    int b = b0 + threadIdx.y + i*8;
    float vv = tile[threadIdx.x][threadIdx.y + i*8];
    dst[(size_t)b*512 + a0 + threadIdx.x] = sqrtf(expf(2.f*vv));
  }
}

__global__ __launch_bounds__(256) void k_cvt(const float* __restrict__ in,
                                             ushort_t* __restrict__ out){
  int i = (blockIdx.x*256 + threadIdx.x)*4;
  float4 v = *(const float4*)(in + i);
  us4 o; o[0]=f2bf(v.x); o[1]=f2bf(v.y); o[2]=f2bf(v.z); o[3]=f2bf(v.w);
  *(us4*)(out + i) = o;
}

// ------------------------------------------------------ rW^T generation ----
// rWT[sl][l][b][a] = normal(e(l,a,b)) * sigT[l][b][a], bf16
__global__ __launch_bounds__(256) void k_genrw(const float* __restrict__ sigT,
                                               const u32* __restrict__ keys,
                                               ushort_t* __restrict__ rWT, int s0){
  int sl = blockIdx.x / 384;
  int bi = blockIdx.x - sl*384;
  int q  = bi*256 + threadIdx.x;     // 0..98303
  int f0 = q*8;                      // flat [l][b][a]
  int lw = f0 >> 18;
  int r  = f0 & 262143;
  int b  = r >> 9;
  int a0 = r & 511;
  const u32* k = keys + (size_t)(s0+sl)*8;
  u32 kh=k[0], kl=k[1];
  u32 eb = (u32)(lw*262144 + a0*512 + b);
  float4 sa = *(const float4*)(sigT + f0);
  float4 sb = *(const float4*)(sigT + f0 + 4);
  float ss[8] = {sa.x,sa.y,sa.z,sa.w,sb.x,sb.y,sb.z,sb.w};
  us8 o;
  #pragma unroll
  for (int j=0;j<8;++j){
    float n = bits_to_normal(jax_bits(kh,kl, eb + (u32)(j*512)));
    o[j] = f2bf(n * ss[j]);
  }
  *(us8*)(rWT + (size_t)sl*786432 + f0) = o;
}

// --------------------------------------------- small weights (bh, Wo, bo) ---
__global__ __launch_bounds__(512) void k_small(const float* __restrict__ mu_bh,
                                               const float* __restrict__ v_bh,
                                               const float* __restrict__ vb_bh,
                                               const float* __restrict__ mu_Wo,
                                               const float* __restrict__ v_Wo,
                                               const float* __restrict__ vo_Wo,
                                               const float* __restrict__ vi_Wo,
                                               const float* __restrict__ mu_bo,
                                               const float* __restrict__ v_bo,
                                               const float* __restrict__ vb_bo,
                                               const u32* __restrict__ keys,
                                               float* __restrict__ bh_all,
                                               float* __restrict__ Wo_all,
                                               float* __restrict__ bo_all){
  int s = blockIdx.x, t = threadIdx.x;
  const u32* k = keys + (size_t)s*8;
  __shared__ __align__(16) float rbh[1536];
  __shared__ __align__(16) float t2[1024];
  for (int e=t; e<1536; e+=512)
    rbh[e] = bits_to_normal(jax_bits(k[2],k[3],(u32)e)) * sqrtf(expf(2.f*v_bh[e]));
  {
    float r0 = bits_to_normal(jax_bits(k[4],k[5],(u32)t))       * sqrtf(expf(2.f*v_Wo[t]));
    float r1 = bits_to_normal(jax_bits(k[4],k[5],(u32)(t+512))) * sqrtf(expf(2.f*v_Wo[t+512]));
    t2[t]     = vo_Wo[0]*r0 + vo_Wo[1]*r1;
    t2[t+512] = vo_Wo[2]*r0 + vo_Wo[3]*r1;
  }
  __syncthreads();
  for (int e=t; e<1536; e+=512){
    int lw = e >> 9;
    const float* row = vb_bh + (size_t)e*512;
    const float* rb = rbh + (lw<<9);
    float acc = 0.f;
    for (int a=0;a<512;a+=4){
      float4 vv = *(const float4*)(row+a);
      acc += vv.x*rb[a] + vv.y*rb[a+1] + vv.z*rb[a+2] + vv.w*rb[a+3];
    }
    bh_all[(size_t)s*1536+e] = acc + mu_bh[e];
  }
  {
    const float* row = vi_Wo + (size_t)t*512;
    float a0=0.f, a1=0.f;
    for (int b=0;b<512;b+=4){
      float4 vv = *(const float4*)(row+b);
      a0 += vv.x*t2[b]    +vv.y*t2[b+1]    +vv.z*t2[b+2]    +vv.w*t2[b+3];
      a1 += vv.x*t2[512+b]+vv.y*t2[512+b+1]+vv.z*t2[512+b+2]+vv.w*t2[512+b+3];
    }
    Wo_all[(size_t)s*1024 + t]       = a0 + mu_Wo[t];
    Wo_all[(size_t)s*1024 + 512 + t] = a1 + mu_Wo[512+t];
  }
  if (t < 2){
    float rb0 = bits_to_normal(jax_bits(k[6],k[7],0u)) * sqrtf(expf(2.f*v_bo[0]));
    float rb1 = bits_to_normal(jax_bits(k[6],k[7],1u)) * sqrtf(expf(2.f*v_bo[1]));
    bo_all[(size_t)s*2+t] = vb_bo[t*2+0]*rb0 + vb_bo[t*2+1]*rb1 + mu_bo[t];
  }
}

// ------------------------------------------- bf16 MFMA NT GEMM (m97-style) --
// C[m,n] = sum_k A[m,k]*B[n,k], A/B bf16 row-major LDA=LDB=512, acc f32.
// EPI: 0 none; 1 += E[m*512+n] (f32); 2 += E[n], relu.  C stored bf16.
template<int EPI>
__device__ __forceinline__ void gemm_core(const ushort_t* __restrict__ A,
                                          const ushort_t* __restrict__ B,
                                          const float* __restrict__ E,
                                          ushort_t* __restrict__ C){
  __shared__ ushort_t As[4096];   // [128][32]
  __shared__ ushort_t Bs[4096];
  const int t = threadIdx.x;
  const int l = t & 63;
  const int m0 = blockIdx.y * 128, n0 = blockIdx.x * 128;
  const int wr = (t >> 7) & 1, wc = (t >> 6) & 1;
  const int srow = t >> 2, scol = (t & 3) << 3;
  const ushort_t* Ag = A + (size_t)(m0 + srow) * 512 + scol;
  const ushort_t* Bg = B + (size_t)(n0 + srow) * 512 + scol;
  ushort_t* Al = As + t * 8;
  ushort_t* Bl = Bs + t * 8;
  const int rfr = l & 15, kfr = (l >> 4) << 3;
  f32x4 acc[4][4] = {};
  for (int k0 = 0; k0 < 512; k0 += 32) {
    gload16(Ag + k0, Al);
    gload16(Ag + 64*512 + k0, Al + 2048);
    gload16(Bg + k0, Bl);
    gload16(Bg + 64*512 + k0, Bl + 2048);
    __syncthreads();
    short8 af[4], bfv[4];
    #pragma unroll
    for (int i=0;i<4;++i){
      af[i]  = *(const short8*)(As + (wr*64 + i*16 + rfr)*32 + kfr);
      bfv[i] = *(const short8*)(Bs + (wc*64 + i*16 + rfr)*32 + kfr);
    }
    #pragma unroll
    for (int i=0;i<4;++i)
      #pragma unroll
      for (int j=0;j<4;++j)
        acc[i][j] = __builtin_amdgcn_mfma_f32_16x16x32_bf16(af[i], bfv[j], acc[i][j], 0, 0, 0);
    __syncthreads();
  }
  const int cr = (l >> 4) << 2, cc = l & 15;
  #pragma unroll
  for (int i=0;i<4;++i){
    #pragma unroll
    for (int j=0;j<4;++j){
      int row = m0 + wr*64 + i*16 + cr;
      int col = n0 + wc*64 + j*16 + cc;
      #pragma unroll
      for (int r=0;r<4;++r){
        float v = acc[i][j][r];
        if (EPI==1) v += E[(size_t)(row+r)*512 + col];
        if (EPI==2) v = fmaxf(v + E[col], 0.f);
        C[(size_t)(row+r)*512 + col] = f2bf(v);
      }
    }
  }
}

// tmp[o][b] = sum_a vo[l][o][a] * rWT[z][b][a]
__global__ __launch_bounds__(256) void k_tmp(const ushort_t* __restrict__ vo,
                                             const ushort_t* __restrict__ rWT,
                                             ushort_t* __restrict__ tmp){
  int z = blockIdx.z, lw = z % 3;
  gemm_core<0>(vo + (size_t)lw*262144, rWT + (size_t)z*262144, nullptr,
               tmp + (size_t)z*262144);
}

// Wh[o][i] = sum_b tmp[z][o][b] * vi[l][i][b] + mu[l][o][i]
__global__ __launch_bounds__(256) void k_wh(const ushort_t* __restrict__ tmp,
                                            const ushort_t* __restrict__ vi,
                                            const float* __restrict__ mu,
                                            ushort_t* __restrict__ Wh){
  int z = blockIdx.z, lw = z % 3;
  gemm_core<1>(tmp + (size_t)z*262144, vi + (size_t)lw*262144,
               mu + (size_t)lw*262144, Wh + (size_t)z*262144);
}

// h' = relu(h @ Wh^T + bh)
__global__ __launch_bounds__(256) void k_fwd(const ushort_t* __restrict__ xbf,
                                             const ushort_t* __restrict__ Wh,
                                             const float* __restrict__ bh_all,
                                             ushort_t* __restrict__ hb, int lw, int s0){
  int sl = blockIdx.z;
  ushort_t* hbase = hb + (size_t)sl*786432;
  const ushort_t* A = (lw==0) ? xbf : (hbase + (lw==2 ? 262144 : 0));
  ushort_t* O = hbase + (lw==1 ? 262144 : 0);
  gemm_core<2>(A, Wh + (size_t)(sl*3+lw)*262144,
               bh_all + (size_t)(s0+sl)*1536 + (size_t)lw*512, O);
}

// out[s][b][c] = h[b,:] . Wo[s][c,:] + bo[s][c]
__global__ __launch_bounds__(256) void k_out(const ushort_t* __restrict__ hb,
                                             const float* __restrict__ Wo_all,
                                             const float* __restrict__ bo_all,
                                             float* __restrict__ out, int s0){
  int sl = blockIdx.x;
  int b = blockIdx.y*256 + threadIdx.x;
  const ushort_t* h = hb + (size_t)sl*786432 + (size_t)b*512;
  int s = s0 + sl;
  const float* W0 = Wo_all + (size_t)s*1024;
  const float* W1 = W0 + 512;
  float a0=0.f, a1=0.f;
  for (int i=0;i<512;i+=8){
    us8 hv = *(const us8*)(h+i);
    #pragma unroll
    for (int j=0;j<8;++j){
      float hf = bf2f(hv[j]);
      a0 = fmaf(hf, W0[i+j], a0);
      a1 = fmaf(hf, W1[i+j], a1);
    }
  }
  out[((size_t)s*512 + b)*2 + 0] = a0 + bo_all[(size_t)s*2+0];
  out[((size_t)s*512 + b)*2 + 1] = a1 + bo_all[(size_t)s*2+1];
}

// ---------------------------------------------------------------- launch ----
extern "C" void kernel_launch(void* const* d_in, const int* in_sizes, int n_in,
                              void* d_out, int out_size, void* d_ws, size_t ws_size,
                              hipStream_t stream){
  const float* x      = (const float*)d_in[0];
  const float* mu_Wh  = (const float*)d_in[1];
  const float* v_Wh   = (const float*)d_in[2];
  const float* vo_Wh  = (const float*)d_in[3];
  const float* vi_Wh  = (const float*)d_in[4];
  const float* mu_bh  = (const float*)d_in[5];
  const float* v_bh   = (const float*)d_in[6];
  const float* vb_bh  = (const float*)d_in[7];
  const float* mu_Wo  = (const float*)d_in[8];
  const float* v_Wo   = (const float*)d_in[9];
  const float* vo_Wo  = (const float*)d_in[10];
  const float* vi_Wo  = (const float*)d_in[11];
  const float* mu_bo  = (const float*)d_in[12];
  const float* v_bo   = (const float*)d_in[13];
  const float* vb_bo  = (const float*)d_in[14];
  float* out = (float*)d_out;

  char* ws = (char*)d_ws;
  // fixed region (8 MB): keys | bh_all | Wo_all | bo_all | sigT | vo_bf | vi_bf | xbf
  u32*      keys   = (u32*)(ws + 0);            // 4800 B
  float*    bh_all = (float*)(ws + 8192);       // 921600 B
  float*    Wo_all = (float*)(ws + 929792);     // 614400 B
  float*    bo_all = (float*)(ws + 1544192);    // 1200 B
  float*    sigT   = (float*)(ws + 1546240);    // 3 MB
  ushort_t* vo_bf  = (ushort_t*)(ws + 4691968); // 1.5 MB
  ushort_t* vi_bf  = (ushort_t*)(ws + 6264832); // 1.5 MB
  ushort_t* xbf    = (ushort_t*)(ws + 7837696); // 0.5 MB
  const size_t big_off = 8388608;
  const size_t per_sample_b = 2u * 1572864u;    // rWT/Wh buf + tmp/h buf (bf16)
  size_t avail = (ws_size > big_off) ? (ws_size - big_off) : 0;
  int C = (int)(avail / per_sample_b);
  if (C < 1) C = 1;
  if (C > NSAMP) C = NSAMP;
  ushort_t* bufRW = (ushort_t*)(ws + big_off);        // [C][3][512][512] rWT -> Wh
  ushort_t* bufT  = bufRW + (size_t)C*786432;         // [C][3][512][512] tmp -> h ping-pong

  hipLaunchKernelGGL(k_keys, dim3(1), dim3(256), 0, stream, keys);
  hipLaunchKernelGGL(k_small, dim3(NSAMP), dim3(512), 0, stream,
                     mu_bh, v_bh, vb_bh, mu_Wo, v_Wo, vo_Wo, vi_Wo,
                     mu_bo, v_bo, vb_bo, keys, bh_all, Wo_all, bo_all);
  hipLaunchKernelGGL(k_sigt, dim3(16,16,3), dim3(32,8), 0, stream, v_Wh, sigT);
  hipLaunchKernelGGL(k_cvt, dim3(768), dim3(256), 0, stream, vo_Wh, vo_bf);
  hipLaunchKernelGGL(k_cvt, dim3(768), dim3(256), 0, stream, vi_Wh, vi_bf);
  hipLaunchKernelGGL(k_cvt, dim3(256), dim3(256), 0, stream, x, xbf);

  for (int s0 = 0; s0 < NSAMP; s0 += C){
    int Cc = (NSAMP - s0 < C) ? (NSAMP - s0) : C;
    hipLaunchKernelGGL(k_genrw, dim3(Cc*384), dim3(256), 0, stream, sigT, keys, bufRW, s0);
    hipLaunchKernelGGL(k_tmp, dim3(4,4,Cc*3), dim3(256), 0, stream, vo_bf, bufRW, bufT);
    hipLaunchKernelGGL(k_wh,  dim3(4,4,Cc*3), dim3(256), 0, stream, bufT, vi_bf, mu_Wh, bufRW);
    for (int lw = 0; lw < 3; ++lw)
      hipLaunchKernelGGL(k_fwd, dim3(4,4,Cc), dim3(256), 0, stream, xbf, bufRW, bh_all, bufT, lw, s0);
    hipLaunchKernelGGL(k_out, dim3(Cc,2), dim3(256), 0, stream, bufT, Wo_all, bo_all, out, s0);
  }
  (void)in_sizes; (void)n_in; (void)out_size;
}

// Round 4
// 1202.416 us; speedup vs baseline: 5.0941x; 1.2304x over previous
//
#include <hip/hip_runtime.h>
#include <hip/hip_bf16.h>
#include <stdint.h>

// ============================================================================
// bayesian_nn round 4: R3 kernel + fast erfinv in k_genrw.
// R3 profile: k_genrw = 43% of total, VALU-issue-bound; libm log1pf was the
// fat (~3.5x instr overhead vs theoretical). Replaced with hw v_log_f32:
//   w = -ln2 * log2((1-x)(1+x))   [abs err ~5e-8 in w -> negligible in output]
// Everything else unchanged from the verified R3 kernel.
// PRNG: JAX partitionable threefry (bit-correct since round 1).
// ============================================================================

#define NSAMP 150

typedef unsigned int u32;
typedef unsigned short ushort_t;
using short8 = __attribute__((ext_vector_type(8))) short;
using us8    = __attribute__((ext_vector_type(8))) unsigned short;
using us4    = __attribute__((ext_vector_type(4))) unsigned short;
using f32x4  = __attribute__((ext_vector_type(4))) float;

// ---------------------------------------------------------------- threefry --
__device__ __forceinline__ u32 rotl32(u32 x, int r){ return (x<<r)|(x>>(32-r)); }

__device__ __forceinline__ void tf_block(u32 k0, u32 k1, u32 x0, u32 x1, u32& o0, u32& o1){
  u32 k2 = k0 ^ k1 ^ 0x1BD11BDAu;
  x0 += k0; x1 += k1;
#define TF_R4(a,b,c,d) \
  x0+=x1; x1=rotl32(x1,a); x1^=x0; \
  x0+=x1; x1=rotl32(x1,b); x1^=x0; \
  x0+=x1; x1=rotl32(x1,c); x1^=x0; \
  x0+=x1; x1=rotl32(x1,d); x1^=x0;
  TF_R4(13,15,26,6)  x0+=k1; x1+=k2+1u;
  TF_R4(17,29,16,24) x0+=k2; x1+=k0+2u;
  TF_R4(13,15,26,6)  x0+=k0; x1+=k1+3u;
  TF_R4(17,29,16,24) x0+=k1; x1+=k2+4u;
  TF_R4(13,15,26,6)  x0+=k2; x1+=k0+5u;
#undef TF_R4
  o0=x0; o1=x1;
}

// partitionable random_bits(key,32,n)[e]: 64-bit counter (0,e), out0^out1
__device__ __forceinline__ u32 jax_bits(u32 kh, u32 kl, u32 e){
  u32 o0,o1; tf_block(kh,kl,0u,e,o0,o1); return o0^o1;
}

// ------------------------------------------------- erfinv + normal map ------
// Exact XLA structure (Giles polynomial) with libm log1pf — used in the small
// one-shot kernels where cost is irrelevant (keeps them bit-identical to R1-R3).
__device__ __forceinline__ float erfinv_xla(float x){
  float w = -log1pf(-x*x);
  float p;
  if (w < 5.0f) {
    w -= 2.5f;
    p =              2.81022636e-08f;
    p = fmaf(p, w,   3.43273939e-07f);
    p = fmaf(p, w,  -3.5233877e-06f);
    p = fmaf(p, w,  -4.39150654e-06f);
    p = fmaf(p, w,   0.00021858087f);
    p = fmaf(p, w,  -0.00125372503f);
    p = fmaf(p, w,  -0.00417768164f);
    p = fmaf(p, w,   0.246640727f);
    p = fmaf(p, w,   1.50140941f);
  } else {
    w = sqrtf(w) - 3.0f;
    p =             -0.000200214257f;
    p = fmaf(p, w,   0.000100950558f);
    p = fmaf(p, w,   0.00134934322f);
    p = fmaf(p, w,  -0.00367342844f);
    p = fmaf(p, w,   0.00573950773f);
    p = fmaf(p, w,  -0.0076224613f);
    p = fmaf(p, w,   0.00943887047f);
    p = fmaf(p, w,   1.00167406f);
    p = fmaf(p, w,   2.83297682f);
  }
  return p * x;
}

// Fast variant for the bulk generator: hw log2 instead of libm log1pf.
// w error ~5e-8 absolute -> output error << bf16 rounding already present.
__device__ __forceinline__ float erfinv_fast(float x){
  float y = (1.0f - x) * (1.0f + x);               // 1 - x^2, keeps precision at |x|->1
  float w = -0.6931471805599453f * __log2f(y);     // -ln(1-x^2) via v_log_f32
  float p;
  if (w < 5.0f) {
    float t = w - 2.5f;
    p =              2.81022636e-08f;
    p = fmaf(p, t,   3.43273939e-07f);
    p = fmaf(p, t,  -3.5233877e-06f);
    p = fmaf(p, t,  -4.39150654e-06f);
    p = fmaf(p, t,   0.00021858087f);
    p = fmaf(p, t,  -0.00125372503f);
    p = fmaf(p, t,  -0.00417768164f);
    p = fmaf(p, t,   0.246640727f);
    p = fmaf(p, t,   1.50140941f);
  } else {
    float t = __fsqrt_rn(w) - 3.0f;
    p =             -0.000200214257f;
    p = fmaf(p, t,   0.000100950558f);
    p = fmaf(p, t,   0.00134934322f);
    p = fmaf(p, t,  -0.00367342844f);
    p = fmaf(p, t,   0.00573950773f);
    p = fmaf(p, t,  -0.0076224613f);
    p = fmaf(p, t,   0.00943887047f);
    p = fmaf(p, t,   1.00167406f);
    p = fmaf(p, t,   2.83297682f);
  }
  return p * x;
}

__device__ __forceinline__ float bits_to_uniform(u32 bits){
  float f = __uint_as_float((bits >> 9) | 0x3F800000u) - 1.0f;   // [0,1)
  const float lo = -0.99999994f;
  float u = fmaf(f, 2.0f, lo);
  return fmaxf(u, lo);
}

__device__ __forceinline__ float bits_to_normal(u32 bits){       // exact path
  return 1.41421356237f * erfinv_xla(bits_to_uniform(bits));
}
__device__ __forceinline__ float bits_to_normal_fast(u32 bits){  // bulk path
  return 1.41421356237f * erfinv_fast(bits_to_uniform(bits));
}

// ------------------------------------------------------------- bf16 utils --
__device__ __forceinline__ ushort_t f2bf(float x){
  u32 u = __float_as_uint(x);
  u32 r = (u + 0x7FFFu + ((u>>16)&1u)) >> 16;
  return (ushort_t)r;
}
__device__ __forceinline__ float bf2f(ushort_t u){ return __uint_as_float(((u32)u)<<16); }

__device__ __forceinline__ void gload16(const void* g, void* l){
  __builtin_amdgcn_global_load_lds((const __attribute__((address_space(1))) void*)g,
                                   (__attribute__((address_space(3))) void*)l, 16, 0, 0);
}

// ------------------------------------------------------------- key kernel --
__global__ void k_keys(u32* __restrict__ keys){
  int s = threadIdx.x;
  if (s >= NSAMP) return;
  u32 sh, sl;
  tf_block(0u,42u,0u,(u32)s,sh,sl);        // foldlike split(key(42),150)
  u32* k = keys + s*8;
  tf_block(sh,sl,0u,0u,k[0],k[1]);
  tf_block(sh,sl,0u,1u,k[2],k[3]);
  tf_block(sh,sl,0u,2u,k[4],k[5]);
  tf_block(sh,sl,0u,3u,k[6],k[7]);
}

// ----------------------------------------------- sigmaT (transpose) + cvt --
// sigT[l][b][a] = sqrt(exp(2*v_Wh[l][a][b]))
__global__ void k_sigt(const float* __restrict__ v, float* __restrict__ sT){
  __shared__ float tile[32][33];
  int lw = blockIdx.z;
  int a0 = blockIdx.y*32, b0 = blockIdx.x*32;
  const float* src = v + (size_t)lw*262144;
  #pragma unroll
  for (int i=0;i<4;++i){
    int a = a0 + threadIdx.y + i*8;
    tile[threadIdx.y + i*8][threadIdx.x] = src[(size_t)a*512 + b0 + threadIdx.x];
  }
  __syncthreads();
  float* dst = sT + (size_t)lw*262144;
  #pragma unroll
  for (int i=0;i<4;++i){
    int b = b0 + threadIdx.y + i*8;
    float vv = tile[threadIdx.x][threadIdx.y + i*8];
    dst[(size_t)b*512 + a0 + threadIdx.x] = sqrtf(expf(2.f*vv));
  }
}

__global__ __launch_bounds__(256) void k_cvt(const float* __restrict__ in,
                                             ushort_t* __restrict__ out){
  int i = (blockIdx.x*256 + threadIdx.x)*4;
  float4 v = *(const float4*)(in + i);
  us4 o; o[0]=f2bf(v.x); o[1]=f2bf(v.y); o[2]=f2bf(v.z); o[3]=f2bf(v.w);
  *(us4*)(out + i) = o;
}

// ------------------------------------------------------ rW^T generation ----
// rWT[sl][l][b][a] = normal(e(l,a,b)) * sigT[l][b][a], bf16
__global__ __launch_bounds__(256) void k_genrw(const float* __restrict__ sigT,
                                               const u32* __restrict__ keys,
                                               ushort_t* __restrict__ rWT, int s0){
  int sl = blockIdx.x / 384;
  int bi = blockIdx.x - sl*384;
  int q  = bi*256 + threadIdx.x;     // 0..98303
  int f0 = q*8;                      // flat [l][b][a]
  int lw = f0 >> 18;
  int r  = f0 & 262143;
  int b  = r >> 9;
  int a0 = r & 511;
  const u32* k = keys + (size_t)(s0+sl)*8;
  u32 kh=k[0], kl=k[1];
  u32 eb = (u32)(lw*262144 + a0*512 + b);
  float4 sa = *(const float4*)(sigT + f0);
  float4 sb = *(const float4*)(sigT + f0 + 4);
  float ss[8] = {sa.x,sa.y,sa.z,sa.w,sb.x,sb.y,sb.z,sb.w};
  us8 o;
  #pragma unroll
  for (int j=0;j<8;++j){
    float n = bits_to_normal_fast(jax_bits(kh,kl, eb + (u32)(j*512)));
    o[j] = f2bf(n * ss[j]);
  }
  *(us8*)(rWT + (size_t)sl*786432 + f0) = o;
}

// --------------------------------------------- small weights (bh, Wo, bo) ---
__global__ __launch_bounds__(512) void k_small(const float* __restrict__ mu_bh,
                                               const float* __restrict__ v_bh,
                                               const float* __restrict__ vb_bh,
                                               const float* __restrict__ mu_Wo,
                                               const float* __restrict__ v_Wo,
                                               const float* __restrict__ vo_Wo,
                                               const float* __restrict__ vi_Wo,
                                               const float* __restrict__ mu_bo,
                                               const float* __restrict__ v_bo,
                                               const float* __restrict__ vb_bo,
                                               const u32* __restrict__ keys,
                                               float* __restrict__ bh_all,
                                               float* __restrict__ Wo_all,
                                               float* __restrict__ bo_all){
  int s = blockIdx.x, t = threadIdx.x;
  const u32* k = keys + (size_t)s*8;
  __shared__ __align__(16) float rbh[1536];
  __shared__ __align__(16) float t2[1024];
  for (int e=t; e<1536; e+=512)
    rbh[e] = bits_to_normal(jax_bits(k[2],k[3],(u32)e)) * sqrtf(expf(2.f*v_bh[e]));
  {
    float r0 = bits_to_normal(jax_bits(k[4],k[5],(u32)t))       * sqrtf(expf(2.f*v_Wo[t]));
    float r1 = bits_to_normal(jax_bits(k[4],k[5],(u32)(t+512))) * sqrtf(expf(2.f*v_Wo[t+512]));
    t2[t]     = vo_Wo[0]*r0 + vo_Wo[1]*r1;
    t2[t+512] = vo_Wo[2]*r0 + vo_Wo[3]*r1;
  }
  __syncthreads();
  for (int e=t; e<1536; e+=512){
    int lw = e >> 9;
    const float* row = vb_bh + (size_t)e*512;
    const float* rb = rbh + (lw<<9);
    float acc = 0.f;
    for (int a=0;a<512;a+=4){
      float4 vv = *(const float4*)(row+a);
      acc += vv.x*rb[a] + vv.y*rb[a+1] + vv.z*rb[a+2] + vv.w*rb[a+3];
    }
    bh_all[(size_t)s*1536+e] = acc + mu_bh[e];
  }
  {
    const float* row = vi_Wo + (size_t)t*512;
    float a0=0.f, a1=0.f;
    for (int b=0;b<512;b+=4){
      float4 vv = *(const float4*)(row+b);
      a0 += vv.x*t2[b]    +vv.y*t2[b+1]    +vv.z*t2[b+2]    +vv.w*t2[b+3];
      a1 += vv.x*t2[512+b]+vv.y*t2[512+b+1]+vv.z*t2[512+b+2]+vv.w*t2[512+b+3];
    }
    Wo_all[(size_t)s*1024 + t]       = a0 + mu_Wo[t];
    Wo_all[(size_t)s*1024 + 512 + t] = a1 + mu_Wo[512+t];
  }
  if (t < 2){
    float rb0 = bits_to_normal(jax_bits(k[6],k[7],0u)) * sqrtf(expf(2.f*v_bo[0]));
    float rb1 = bits_to_normal(jax_bits(k[6],k[7],1u)) * sqrtf(expf(2.f*v_bo[1]));
    bo_all[(size_t)s*2+t] = vb_bo[t*2+0]*rb0 + vb_bo[t*2+1]*rb1 + mu_bo[t];
  }
}

// ------------------------------------------- bf16 MFMA NT GEMM (m97-style) --
// C[m,n] = sum_k A[m,k]*B[n,k], A/B bf16 row-major LDA=LDB=512, acc f32.
// EPI: 0 none; 1 += E[m*512+n] (f32); 2 += E[n], relu.  C stored bf16.
template<int EPI>
__device__ __forceinline__ void gemm_core(const ushort_t* __restrict__ A,
                                          const ushort_t* __restrict__ B,
                                          const float* __restrict__ E,
                                          ushort_t* __restrict__ C){
  __shared__ ushort_t As[4096];   // [128][32]
  __shared__ ushort_t Bs[4096];
  const int t = threadIdx.x;
  const int l = t & 63;
  const int m0 = blockIdx.y * 128, n0 = blockIdx.x * 128;
  const int wr = (t >> 7) & 1, wc = (t >> 6) & 1;
  const int srow = t >> 2, scol = (t & 3) << 3;
  const ushort_t* Ag = A + (size_t)(m0 + srow) * 512 + scol;
  const ushort_t* Bg = B + (size_t)(n0 + srow) * 512 + scol;
  ushort_t* Al = As + t * 8;
  ushort_t* Bl = Bs + t * 8;
  const int rfr = l & 15, kfr = (l >> 4) << 3;
  f32x4 acc[4][4] = {};
  for (int k0 = 0; k0 < 512; k0 += 32) {
    gload16(Ag + k0, Al);
    gload16(Ag + 64*512 + k0, Al + 2048);
    gload16(Bg + k0, Bl);
    gload16(Bg + 64*512 + k0, Bl + 2048);
    __syncthreads();
    short8 af[4], bfv[4];
    #pragma unroll
    for (int i=0;i<4;++i){
      af[i]  = *(const short8*)(As + (wr*64 + i*16 + rfr)*32 + kfr);
      bfv[i] = *(const short8*)(Bs + (wc*64 + i*16 + rfr)*32 + kfr);
    }
    #pragma unroll
    for (int i=0;i<4;++i)
      #pragma unroll
      for (int j=0;j<4;++j)
        acc[i][j] = __builtin_amdgcn_mfma_f32_16x16x32_bf16(af[i], bfv[j], acc[i][j], 0, 0, 0);
    __syncthreads();
  }
  const int cr = (l >> 4) << 2, cc = l & 15;
  #pragma unroll
  for (int i=0;i<4;++i){
    #pragma unroll
    for (int j=0;j<4;++j){
      int row = m0 + wr*64 + i*16 + cr;
      int col = n0 + wc*64 + j*16 + cc;
      #pragma unroll
      for (int r=0;r<4;++r){
        float v = acc[i][j][r];
        if (EPI==1) v += E[(size_t)(row+r)*512 + col];
        if (EPI==2) v = fmaxf(v + E[col], 0.f);
        C[(size_t)(row+r)*512 + col] = f2bf(v);
      }
    }
  }
}

// tmp[o][b] = sum_a vo[l][o][a] * rWT[z][b][a]
__global__ __launch_bounds__(256) void k_tmp(const ushort_t* __restrict__ vo,
                                             const ushort_t* __restrict__ rWT,
                                             ushort_t* __restrict__ tmp){
  int z = blockIdx.z, lw = z % 3;
  gemm_core<0>(vo + (size_t)lw*262144, rWT + (size_t)z*262144, nullptr,
               tmp + (size_t)z*262144);
}

// Wh[o][i] = sum_b tmp[z][o][b] * vi[l][i][b] + mu[l][o][i]
__global__ __launch_bounds__(256) void k_wh(const ushort_t* __restrict__ tmp,
                                            const ushort_t* __restrict__ vi,
                                            const float* __restrict__ mu,
                                            ushort_t* __restrict__ Wh){
  int z = blockIdx.z, lw = z % 3;
  gemm_core<1>(tmp + (size_t)z*262144, vi + (size_t)lw*262144,
               mu + (size_t)lw*262144, Wh + (size_t)z*262144);
}

// h' = relu(h @ Wh^T + bh)
__global__ __launch_bounds__(256) void k_fwd(const ushort_t* __restrict__ xbf,
                                             const ushort_t* __restrict__ Wh,
                                             const float* __restrict__ bh_all,
                                             ushort_t* __restrict__ hb, int lw, int s0){
  int sl = blockIdx.z;
  ushort_t* hbase = hb + (size_t)sl*786432;
  const ushort_t* A = (lw==0) ? xbf : (hbase + (lw==2 ? 262144 : 0));
  ushort_t* O = hbase + (lw==1 ? 262144 : 0);
  gemm_core<2>(A, Wh + (size_t)(sl*3+lw)*262144,
               bh_all + (size_t)(s0+sl)*1536 + (size_t)lw*512, O);
}

// out[s][b][c] = h[b,:] . Wo[s][c,:] + bo[s][c]
__global__ __launch_bounds__(256) void k_out(const ushort_t* __restrict__ hb,
                                             const float* __restrict__ Wo_all,
                                             const float* __restrict__ bo_all,
                                             float* __restrict__ out, int s0){
  int sl = blockIdx.x;
  int b = blockIdx.y*256 + threadIdx.x;
  const ushort_t* h = hb + (size_t)sl*786432 + (size_t)b*512;
  int s = s0 + sl;
  const float* W0 = Wo_all + (size_t)s*1024;
  const float* W1 = W0 + 512;
  float a0=0.f, a1=0.f;
  for (int i=0;i<512;i+=8){
    us8 hv = *(const us8*)(h+i);
    #pragma unroll
    for (int j=0;j<8;++j){
      float hf = bf2f(hv[j]);
      a0 = fmaf(hf, W0[i+j], a0);
      a1 = fmaf(hf, W1[i+j], a1);
    }
  }
  out[((size_t)s*512 + b)*2 + 0] = a0 + bo_all[(size_t)s*2+0];
  out[((size_t)s*512 + b)*2 + 1] = a1 + bo_all[(size_t)s*2+1];
}

// ---------------------------------------------------------------- launch ----
extern "C" void kernel_launch(void* const* d_in, const int* in_sizes, int n_in,
                              void* d_out, int out_size, void* d_ws, size_t ws_size,
                              hipStream_t stream){
  const float* x      = (const float*)d_in[0];
  const float* mu_Wh  = (const float*)d_in[1];
  const float* v_Wh   = (const float*)d_in[2];
  const float* vo_Wh  = (const float*)d_in[3];
  const float* vi_Wh  = (const float*)d_in[4];
  const float* mu_bh  = (const float*)d_in[5];
  const float* v_bh   = (const float*)d_in[6];
  const float* vb_bh  = (const float*)d_in[7];
  const float* mu_Wo  = (const float*)d_in[8];
  const float* v_Wo   = (const float*)d_in[9];
  const float* vo_Wo  = (const float*)d_in[10];
  const float* vi_Wo  = (const float*)d_in[11];
  const float* mu_bo  = (const float*)d_in[12];
  const float* v_bo   = (const float*)d_in[13];
  const float* vb_bo  = (const float*)d_in[14];
  float* out = (float*)d_out;

  char* ws = (char*)d_ws;
  // fixed region (8 MB): keys | bh_all | Wo_all | bo_all | sigT | vo_bf | vi_bf | xbf
  u32*      keys   = (u32*)(ws + 0);            // 4800 B
  float*    bh_all = (float*)(ws + 8192);       // 921600 B
  float*    Wo_all = (float*)(ws + 929792);     // 614400 B
  float*    bo_all = (float*)(ws + 1544192);    // 1200 B
  float*    sigT   = (float*)(ws + 1546240);    // 3 MB
  ushort_t* vo_bf  = (ushort_t*)(ws + 4691968); // 1.5 MB
  ushort_t* vi_bf  = (ushort_t*)(ws + 6264832); // 1.5 MB
  ushort_t* xbf    = (ushort_t*)(ws + 7837696); // 0.5 MB
  const size_t big_off = 8388608;
  const size_t per_sample_b = 2u * 1572864u;    // rWT/Wh buf + tmp/h buf (bf16)
  size_t avail = (ws_size > big_off) ? (ws_size - big_off) : 0;
  int C = (int)(avail / per_sample_b);
  if (C < 1) C = 1;
  if (C > NSAMP) C = NSAMP;
  ushort_t* bufRW = (ushort_t*)(ws + big_off);        // [C][3][512][512] rWT -> Wh
  ushort_t* bufT  = bufRW + (size_t)C*786432;         // [C][3][512][512] tmp -> h ping-pong

  hipLaunchKernelGGL(k_keys, dim3(1), dim3(256), 0, stream, keys);
  hipLaunchKernelGGL(k_small, dim3(NSAMP), dim3(512), 0, stream,
                     mu_bh, v_bh, vb_bh, mu_Wo, v_Wo, vo_Wo, vi_Wo,
                     mu_bo, v_bo, vb_bo, keys, bh_all, Wo_all, bo_all);
  hipLaunchKernelGGL(k_sigt, dim3(16,16,3), dim3(32,8), 0, stream, v_Wh, sigT);
  hipLaunchKernelGGL(k_cvt, dim3(768), dim3(256), 0, stream, vo_Wh, vo_bf);
  hipLaunchKernelGGL(k_cvt, dim3(768), dim3(256), 0, stream, vi_Wh, vi_bf);
  hipLaunchKernelGGL(k_cvt, dim3(256), dim3(256), 0, stream, x, xbf);

  for (int s0 = 0; s0 < NSAMP; s0 += C){
    int Cc = (NSAMP - s0 < C) ? (NSAMP - s0) : C;
    hipLaunchKernelGGL(k_genrw, dim3(Cc*384), dim3(256), 0, stream, sigT, keys, bufRW, s0);
    hipLaunchKernelGGL(k_tmp, dim3(4,4,Cc*3), dim3(256), 0, stream, vo_bf, bufRW, bufT);
    hipLaunchKernelGGL(k_wh,  dim3(4,4,Cc*3), dim3(256), 0, stream, bufT, vi_bf, mu_Wh, bufRW);
    for (int lw = 0; lw < 3; ++lw)
      hipLaunchKernelGGL(k_fwd, dim3(4,4,Cc), dim3(256), 0, stream, xbf, bufRW, bh_all, bufT, lw, s0);
    hipLaunchKernelGGL(k_out, dim3(Cc,2), dim3(256), 0, stream, bufT, Wo_all, bo_all, out, s0);
  }
  (void)in_sizes; (void)n_in; (void)out_size;
}